// Round 7
// baseline (381.488 us; speedup 1.0000x reference)
//
#include <hip/hip_runtime.h>
#include <stdint.h>

// Problem: B=2, S=2048, D=1024, H=16, dh=64
// Inputs fp32, OUTPUT fp32. Internals bf16 (threshold has bf16 floor).
#define SEQ    2048
#define DMODEL 1024

typedef __bf16 bf16x8 __attribute__((ext_vector_type(8)));
typedef float  f32x4  __attribute__((ext_vector_type(4)));

typedef __attribute__((address_space(1))) const void CGV;  // global
typedef __attribute__((address_space(3))) void LDSV;       // LDS

__device__ __forceinline__ void load_lds16(const void* g, void* l) {
    __builtin_amdgcn_global_load_lds((CGV*)g, (LDSV*)l, 16, 0, 0);
}

// ---------------------------------------------------------------------------
// Transpose+convert: in f32 [R][C] -> out bf16 [C][R].  grid (C/32, R/32), 256 thr
// ---------------------------------------------------------------------------
__global__ __launch_bounds__(256)
void transpose_f32_to_bf16(const float* __restrict__ in, __bf16* __restrict__ out,
                           int R, int C)
{
    __shared__ float tile[32][33];
    const int t  = threadIdx.x;
    const int tx = t & 31, ty = t >> 5;          // ty 0..7
    const int c0 = blockIdx.x * 32;
    const int r0 = blockIdx.y * 32;
#pragma unroll
    for (int i = 0; i < 4; ++i)
        tile[ty + i * 8][tx] = in[(size_t)(r0 + ty + i * 8) * C + c0 + tx];
    __syncthreads();
#pragma unroll
    for (int i = 0; i < 4; ++i)
        out[(size_t)(c0 + ty + i * 8) * R + r0 + tx] = (__bf16)tile[tx][ty + i * 8];
}

// ---------------------------------------------------------------------------
// V transpose (bf16): in [32][2048][64] -> out [32][64][2048]
// grid (SEQ/32, 64/32, 32), 256 thr
// ---------------------------------------------------------------------------
__global__ __launch_bounds__(256)
void transpose_v(const __bf16* __restrict__ in, __bf16* __restrict__ out)
{
    __shared__ __bf16 tile[32][34];
    const int t  = threadIdx.x;
    const int tx = t & 31, ty = t >> 5;
    const int s0 = blockIdx.x * 32;
    const int d0 = blockIdx.y * 32;
    const int bh = blockIdx.z;
    const __bf16* ip = in  + (size_t)bh * SEQ * 64;
    __bf16*       op = out + (size_t)bh * 64 * SEQ;
#pragma unroll
    for (int i = 0; i < 4; ++i)
        tile[ty + i * 8][tx] = ip[(size_t)(s0 + ty + i * 8) * 64 + d0 + tx];
    __syncthreads();
#pragma unroll
    for (int i = 0; i < 4; ++i)
        op[(size_t)(d0 + ty + i * 8) * SEQ + s0 + tx] = tile[tx][ty + i * 8];
}

// ---------------------------------------------------------------------------
// GEMM (m97 structure): C[M x N] = A[M x K] @ Bt[N x K]^T + bias[N]
// (unchanged from R6 PASS)
// ---------------------------------------------------------------------------
template<bool A_IS_F32>
__global__ __launch_bounds__(256)
void gemm_kernel(const void* __restrict__ Av, const __bf16* __restrict__ Bt,
                 const float* __restrict__ bias,
                 __bf16* __restrict__ Cq, __bf16* __restrict__ Ck,
                 __bf16* __restrict__ Cv, float* __restrict__ Cplain,
                 int K, int N, int mode)
{
    __shared__ __attribute__((aligned(16))) __bf16 As[128][32];
    __shared__ __attribute__((aligned(16))) __bf16 Bs[128][32];

    const int t    = threadIdx.x;
    const int wave = __builtin_amdgcn_readfirstlane(t >> 6);
    const int lane = t & 63;
    const int l15  = lane & 15;
    const int quad = lane >> 4;
    const int wm   = (wave >> 1) * 64;
    const int wn   = (wave & 1) * 64;
    const int m0   = blockIdx.y * 128;
    const int n0   = blockIdx.x * 128;

    const int arow  = lane >> 2;
    const int akoff = (lane & 3) * 8;

    f32x4 acc[4][4] = {};

    for (int k0 = 0; k0 < K; k0 += 32) {
        __syncthreads();
        if (A_IS_F32) {
            const float* A = (const float*)Av;
            int row = t >> 1, kk = (t & 1) * 16;
            const float* srcp = A + (size_t)(m0 + row) * K + k0 + kk;
            float4 v0 = *(const float4*)(srcp);
            float4 v1 = *(const float4*)(srcp + 4);
            float4 v2 = *(const float4*)(srcp + 8);
            float4 v3 = *(const float4*)(srcp + 12);
            __bf16 tmp[16] = {
                (__bf16)v0.x, (__bf16)v0.y, (__bf16)v0.z, (__bf16)v0.w,
                (__bf16)v1.x, (__bf16)v1.y, (__bf16)v1.z, (__bf16)v1.w,
                (__bf16)v2.x, (__bf16)v2.y, (__bf16)v2.z, (__bf16)v2.w,
                (__bf16)v3.x, (__bf16)v3.y, (__bf16)v3.z, (__bf16)v3.w };
            *(uint4*)(&As[row][kk])     = *(uint4*)(tmp);
            *(uint4*)(&As[row][kk + 8]) = *(uint4*)(tmp + 8);
        } else {
            const __bf16* A = (const __bf16*)Av;
#pragma unroll
            for (int p = 0; p < 2; ++p) {
                int slab = (wave * 2 + p) * 16;
                const __bf16* g = A + (size_t)(m0 + slab + arow) * K + k0 + akoff;
                load_lds16(g, &As[slab][0]);
            }
        }
#pragma unroll
        for (int p = 0; p < 2; ++p) {
            int slab = (wave * 2 + p) * 16;
            const __bf16* g = Bt + (size_t)(n0 + slab + arow) * K + k0 + akoff;
            load_lds16(g, &Bs[slab][0]);
        }
        __syncthreads();

        bf16x8 af[4], bfr[4];
#pragma unroll
        for (int mi = 0; mi < 4; ++mi)
            af[mi] = *(const bf16x8*)(&As[wm + mi * 16 + l15][quad * 8]);
#pragma unroll
        for (int ni = 0; ni < 4; ++ni)
            bfr[ni] = *(const bf16x8*)(&Bs[wn + ni * 16 + l15][quad * 8]);
#pragma unroll
        for (int mi = 0; mi < 4; ++mi)
#pragma unroll
            for (int ni = 0; ni < 4; ++ni)
                acc[mi][ni] = __builtin_amdgcn_mfma_f32_16x16x32_bf16(
                    af[mi], bfr[ni], acc[mi][ni], 0, 0, 0);
    }

#pragma unroll
    for (int mi = 0; mi < 4; ++mi) {
        int rowb = m0 + wm + mi * 16 + quad * 4;
#pragma unroll
        for (int ni = 0; ni < 4; ++ni) {
            int col = n0 + wn + ni * 16 + l15;
            float bia = bias[col];
#pragma unroll
            for (int r = 0; r < 4; ++r) {
                float v = acc[mi][ni][r] + bia;
                int rr = rowb + r;
                if (mode == 0) {
                    int b = rr >> 11;
                    int s = rr & 2047;
                    int part = col >> 10;
                    int rem  = col & 1023;
                    int h = rem >> 6;
                    int d = rem & 63;
                    __bf16* dst = (part == 0) ? Cq : (part == 1) ? Ck : Cv;
                    dst[(((size_t)(b * 16 + h)) * SEQ + s) * 64 + d] = (__bf16)v;
                } else {
                    Cplain[(size_t)rr * N + col] = v;
                }
            }
        }
    }
}

// ---------------------------------------------------------------------------
// MFMA flash attention, pipelined:
//  - ONE barrier per iter (Ps is wave-private: no barrier; Vt double-buffered)
//  - K fragments + mask values software-prefetched one iter ahead
// grid (B*H=32, S/64=32); 4 waves, each wave owns 16 q rows.
// ---------------------------------------------------------------------------
__global__ __launch_bounds__(256)
void attn_kernel(const __bf16* __restrict__ Q, const __bf16* __restrict__ Kb,
                 const __bf16* __restrict__ Vtg, const float* __restrict__ mask,
                 __bf16* __restrict__ Out)
{
    __shared__ __attribute__((aligned(16))) __bf16 Vt[2][64][72];  // dbuf [d][key]
    __shared__ __attribute__((aligned(16))) __bf16 Ps[4][16][72];  // wave-private P

    const int t    = threadIdx.x;
    const int wave = t >> 6;
    const int lane = t & 63;
    const int l15  = lane & 15;
    const int quad = lane >> 4;
    const int bh   = blockIdx.x;
    const int b    = bh >> 4;
    const int h    = bh & 15;
    const int q0   = blockIdx.y * 64 + wave * 16;

    const __bf16* Qp  = Q   + (size_t)bh * SEQ * 64;
    const __bf16* Kp  = Kb  + (size_t)bh * SEQ * 64;
    const __bf16* Vtp = Vtg + (size_t)bh * 64 * SEQ;   // [d][s]
    const float*  Mp  = mask + (size_t)b * SEQ * SEQ;

    // loop-invariant mask row pointers (4 q-rows per lane)
    const float* mrow[4];
#pragma unroll
    for (int r = 0; r < 4; ++r)
        mrow[r] = Mp + (size_t)(q0 + quad * 4 + r) * SEQ;

    bf16x8 qf[2];
#pragma unroll
    for (int ks = 0; ks < 2; ++ks)
        qf[ks] = *(const bf16x8*)(Qp + (size_t)(q0 + l15) * 64 + ks * 32 + quad * 8);

    // prefetch iter-0 K fragments + mask values
    bf16x8 kf0[4], kf1[4];
    float  mv[4][4];
#pragma unroll
    for (int nb = 0; nb < 4; ++nb) {
        const __bf16* kp = Kp + (size_t)(nb * 16 + l15) * 64;
        kf0[nb] = *(const bf16x8*)(kp + quad * 8);
        kf1[nb] = *(const bf16x8*)(kp + 32 + quad * 8);
#pragma unroll
        for (int r = 0; r < 4; ++r)
            mv[nb][r] = mrow[r][nb * 16 + l15];
    }

    f32x4 oacc[4] = {};
    float mrun[4], lrun[4];
#pragma unroll
    for (int r = 0; r < 4; ++r) { mrun[r] = -1e30f; lrun[r] = 0.f; }

    const int NT = SEQ / 64;
    for (int kt = 0; kt < NT; ++kt) {
        const int key0 = kt * 64;
        const int buf  = kt & 1;
        // ---- stage V^T tile into Vt[buf] (coalesced; dbuf => no barrier) ----
        {
            int idx = t * 8;
#pragma unroll
            for (int it2 = 0; it2 < 2; ++it2) {
                int d  = idx >> 6;
                int ky = idx & 63;
                *(uint4*)(&Vt[buf][d][ky]) =
                    *(const uint4*)(Vtp + (size_t)d * SEQ + key0 + ky);
                idx += 2048;
            }
        }
        // ---- S = Q K^T using prefetched fragments ----
        f32x4 sa[4];
#pragma unroll
        for (int nb = 0; nb < 4; ++nb) {
            f32x4 z = {};
            z = __builtin_amdgcn_mfma_f32_16x16x32_bf16(qf[0], kf0[nb], z, 0, 0, 0);
            z = __builtin_amdgcn_mfma_f32_16x16x32_bf16(qf[1], kf1[nb], z, 0, 0, 0);
            sa[nb] = z;
        }
        // ---- masked scores (prefetched mask values) ----
        float s[4][4];
#pragma unroll
        for (int nb = 0; nb < 4; ++nb)
#pragma unroll
            for (int r = 0; r < 4; ++r)
                s[nb][r] = sa[nb][r] * 0.125f * mv[nb][r] + (mv[nb][r] - 1.0f) * 10000.0f;

        // ---- prefetch next iter's K fragments + mask (overlaps softmax/PV) ----
        {
            const int keyn = (kt + 1 < NT) ? (kt + 1) * 64 : 0;
#pragma unroll
            for (int nb = 0; nb < 4; ++nb) {
                const __bf16* kp = Kp + (size_t)(keyn + nb * 16 + l15) * 64;
                kf0[nb] = *(const bf16x8*)(kp + quad * 8);
                kf1[nb] = *(const bf16x8*)(kp + 32 + quad * 8);
#pragma unroll
                for (int r = 0; r < 4; ++r)
                    mv[nb][r] = mrow[r][keyn + nb * 16 + l15];
            }
        }

        // ---- online softmax: row = (quad,reg); reduce across 16 lanes ----
        float alpha[4];
#pragma unroll
        for (int r = 0; r < 4; ++r) {
            float v = fmaxf(fmaxf(s[0][r], s[1][r]), fmaxf(s[2][r], s[3][r]));
            v = fmaxf(v, __shfl_xor(v, 1));
            v = fmaxf(v, __shfl_xor(v, 2));
            v = fmaxf(v, __shfl_xor(v, 4));
            v = fmaxf(v, __shfl_xor(v, 8));
            float mnew = fmaxf(mrun[r], v);
            alpha[r] = __expf(mrun[r] - mnew);
            mrun[r] = mnew;
        }
#pragma unroll
        for (int r = 0; r < 4; ++r) {
            float accs = 0.f;
#pragma unroll
            for (int nb = 0; nb < 4; ++nb) {
                float p = __expf(s[nb][r] - mrun[r]);
                s[nb][r] = p;
                accs += p;
            }
            accs += __shfl_xor(accs, 1);
            accs += __shfl_xor(accs, 2);
            accs += __shfl_xor(accs, 4);
            accs += __shfl_xor(accs, 8);
            lrun[r] = lrun[r] * alpha[r] + accs;
        }
        // ---- P: C-layout -> wave-private LDS (no barrier needed) ----
#pragma unroll
        for (int nb = 0; nb < 4; ++nb)
#pragma unroll
            for (int r = 0; r < 4; ++r)
                Ps[wave][quad * 4 + r][nb * 16 + l15] = (__bf16)s[nb][r];

        __syncthreads();   // single barrier: all waves' Vt[buf] writes visible

        // ---- O = O*alpha + P V ----
#pragma unroll
        for (int cb = 0; cb < 4; ++cb)
#pragma unroll
            for (int r = 0; r < 4; ++r)
                oacc[cb][r] *= alpha[r];
        bf16x8 pf[2];
#pragma unroll
        for (int ks = 0; ks < 2; ++ks)
            pf[ks] = *(const bf16x8*)(&Ps[wave][l15][ks * 32 + quad * 8]);
#pragma unroll
        for (int cb = 0; cb < 4; ++cb) {
#pragma unroll
            for (int ks = 0; ks < 2; ++ks) {
                bf16x8 vf = *(const bf16x8*)(&Vt[buf][cb * 16 + l15][ks * 32 + quad * 8]);
                oacc[cb] = __builtin_amdgcn_mfma_f32_16x16x32_bf16(pf[ks], vf, oacc[cb], 0, 0, 0);
            }
        }
    }
    // epilogue (bf16 Ao, feeds GEMM2's global_load_lds A path)
#pragma unroll
    for (int cb = 0; cb < 4; ++cb) {
#pragma unroll
        for (int r = 0; r < 4; ++r) {
            int qq = q0 + quad * 4 + r;
            float v = oacc[cb][r] / lrun[r];
            Out[((size_t)(b * SEQ + qq)) * DMODEL + h * 64 + cb * 16 + l15] = (__bf16)v;
        }
    }
}

// ---------------------------------------------------------------------------
extern "C" void kernel_launch(void* const* d_in, const int* in_sizes, int n_in,
                              void* d_out, int out_size, void* d_ws, size_t ws_size,
                              hipStream_t stream)
{
    const float* src  = nullptr;  // 4194304
    const float* mask = nullptr;  // 8388608
    const float* Wqkv = nullptr;  // 3145728
    const float* bqkv = nullptr;  // 3072
    const float* Wout = nullptr;  // 1048576
    const float* bout = nullptr;  // 1024
    for (int i = 0; i < n_in; ++i) {
        switch (in_sizes[i]) {
            case 4194304: src  = (const float*)d_in[i]; break;
            case 8388608: mask = (const float*)d_in[i]; break;
            case 3145728: Wqkv = (const float*)d_in[i]; break;
            case 3072:    bqkv = (const float*)d_in[i]; break;
            case 1048576: Wout = (const float*)d_in[i]; break;
            case 1024:    bout = (const float*)d_in[i]; break;
        }
    }
    float* out = (float*)d_out;                  // [2,2048,1024] fp32

    const size_t NE = (size_t)2 * 16 * SEQ * 64; // 4M elems
    __bf16* Qb     = (__bf16*)d_ws;              // 4M
    __bf16* Kb     = Qb + NE;                    // 4M
    __bf16* Vb     = Kb + NE;                    // 4M (dead after transpose_v)
    __bf16* Vtg    = Vb + NE;                    // 4M
    __bf16* Wqkv_t = Vtg + NE;                   // 3M  [3072][1024]
    __bf16* Wout_t = Wqkv_t + (size_t)3072 * 1024; // 1M [1024][1024]
    __bf16* Ao     = Vb;                         // alias: Vb dead by then

    transpose_f32_to_bf16<<<dim3(3072 / 32, 1024 / 32), 256, 0, stream>>>(
        Wqkv, Wqkv_t, 1024, 3072);
    transpose_f32_to_bf16<<<dim3(1024 / 32, 1024 / 32), 256, 0, stream>>>(
        Wout, Wout_t, 1024, 1024);

    gemm_kernel<true><<<dim3(3072 / 128, 4096 / 128), 256, 0, stream>>>(
        (const void*)src, Wqkv_t, bqkv, Qb, Kb, Vb, nullptr, 1024, 3072, 0);

    transpose_v<<<dim3(SEQ / 32, 2, 32), 256, 0, stream>>>(Vb, Vtg);

    attn_kernel<<<dim3(32, SEQ / 64), 256, 0, stream>>>(Qb, Kb, Vtg, mask, Ao);

    gemm_kernel<false><<<dim3(1024 / 128, 4096 / 128), 256, 0, stream>>>(
        (const void*)Ao, Wout_t, bout, nullptr, nullptr, nullptr, out, 1024, 1024, 1);
}

// Round 8
// 360.911 us; speedup vs baseline: 1.0570x; 1.0570x over previous
//
#include <hip/hip_runtime.h>
#include <stdint.h>

// Problem: B=2, S=2048, D=1024, H=16, dh=64
// Inputs fp32, OUTPUT fp32. Internals bf16 (threshold has bf16 floor).
#define SEQ    2048
#define DMODEL 1024

typedef __bf16 bf16x8 __attribute__((ext_vector_type(8)));
typedef float  f32x4  __attribute__((ext_vector_type(4)));

typedef __attribute__((address_space(1))) const void CGV;  // global
typedef __attribute__((address_space(3))) void LDSV;       // LDS

__device__ __forceinline__ void load_lds16(const void* g, void* l) {
    __builtin_amdgcn_global_load_lds((CGV*)g, (LDSV*)l, 16, 0, 0);
}

// ---------------------------------------------------------------------------
// Transpose+convert: in f32 [R][C] -> out bf16 [C][R].  grid (C/32, R/32), 256
// ---------------------------------------------------------------------------
__global__ __launch_bounds__(256)
void transpose_f32_to_bf16(const float* __restrict__ in, __bf16* __restrict__ out,
                           int R, int C)
{
    __shared__ float tile[32][33];
    const int t  = threadIdx.x;
    const int tx = t & 31, ty = t >> 5;
    const int c0 = blockIdx.x * 32;
    const int r0 = blockIdx.y * 32;
#pragma unroll
    for (int i = 0; i < 4; ++i)
        tile[ty + i * 8][tx] = in[(size_t)(r0 + ty + i * 8) * C + c0 + tx];
    __syncthreads();
#pragma unroll
    for (int i = 0; i < 4; ++i)
        out[(size_t)(c0 + ty + i * 8) * R + r0 + tx] = (__bf16)tile[tx][ty + i * 8];
}

// ---------------------------------------------------------------------------
// GEMM (m97 structure): C[M x N] = A[M x K] @ Bt[N x K]^T + bias[N]
// mode 0: scatter bf16 Q/K -> [B,H,S,dh]; V -> TRANSPOSED [B,H,dh,S]
// mode 1: fp32 row-major store
// ---------------------------------------------------------------------------
template<bool A_IS_F32>
__global__ __launch_bounds__(256)
void gemm_kernel(const void* __restrict__ Av, const __bf16* __restrict__ Bt,
                 const float* __restrict__ bias,
                 __bf16* __restrict__ Cq, __bf16* __restrict__ Ck,
                 __bf16* __restrict__ Cv, float* __restrict__ Cplain,
                 int K, int N, int mode)
{
    __shared__ __attribute__((aligned(16))) __bf16 As[128][32];
    __shared__ __attribute__((aligned(16))) __bf16 Bs[128][32];

    const int t    = threadIdx.x;
    const int wave = __builtin_amdgcn_readfirstlane(t >> 6);
    const int lane = t & 63;
    const int l15  = lane & 15;
    const int quad = lane >> 4;
    const int wm   = (wave >> 1) * 64;
    const int wn   = (wave & 1) * 64;
    const int m0   = blockIdx.y * 128;
    const int n0   = blockIdx.x * 128;

    const int arow  = lane >> 2;
    const int akoff = (lane & 3) * 8;

    f32x4 acc[4][4] = {};

    for (int k0 = 0; k0 < K; k0 += 32) {
        __syncthreads();
        if (A_IS_F32) {
            const float* A = (const float*)Av;
            int row = t >> 1, kk = (t & 1) * 16;
            const float* srcp = A + (size_t)(m0 + row) * K + k0 + kk;
            float4 v0 = *(const float4*)(srcp);
            float4 v1 = *(const float4*)(srcp + 4);
            float4 v2 = *(const float4*)(srcp + 8);
            float4 v3 = *(const float4*)(srcp + 12);
            __bf16 tmp[16] = {
                (__bf16)v0.x, (__bf16)v0.y, (__bf16)v0.z, (__bf16)v0.w,
                (__bf16)v1.x, (__bf16)v1.y, (__bf16)v1.z, (__bf16)v1.w,
                (__bf16)v2.x, (__bf16)v2.y, (__bf16)v2.z, (__bf16)v2.w,
                (__bf16)v3.x, (__bf16)v3.y, (__bf16)v3.z, (__bf16)v3.w };
            *(uint4*)(&As[row][kk])     = *(uint4*)(tmp);
            *(uint4*)(&As[row][kk + 8]) = *(uint4*)(tmp + 8);
        } else {
            const __bf16* A = (const __bf16*)Av;
#pragma unroll
            for (int p = 0; p < 2; ++p) {
                int slab = (wave * 2 + p) * 16;
                const __bf16* g = A + (size_t)(m0 + slab + arow) * K + k0 + akoff;
                load_lds16(g, &As[slab][0]);
            }
        }
#pragma unroll
        for (int p = 0; p < 2; ++p) {
            int slab = (wave * 2 + p) * 16;
            const __bf16* g = Bt + (size_t)(n0 + slab + arow) * K + k0 + akoff;
            load_lds16(g, &Bs[slab][0]);
        }
        __syncthreads();

        bf16x8 af[4], bfr[4];
#pragma unroll
        for (int mi = 0; mi < 4; ++mi)
            af[mi] = *(const bf16x8*)(&As[wm + mi * 16 + l15][quad * 8]);
#pragma unroll
        for (int ni = 0; ni < 4; ++ni)
            bfr[ni] = *(const bf16x8*)(&Bs[wn + ni * 16 + l15][quad * 8]);
#pragma unroll
        for (int mi = 0; mi < 4; ++mi)
#pragma unroll
            for (int ni = 0; ni < 4; ++ni)
                acc[mi][ni] = __builtin_amdgcn_mfma_f32_16x16x32_bf16(
                    af[mi], bfr[ni], acc[mi][ni], 0, 0, 0);
    }

#pragma unroll
    for (int mi = 0; mi < 4; ++mi) {
        int rowb = m0 + wm + mi * 16 + quad * 4;
#pragma unroll
        for (int ni = 0; ni < 4; ++ni) {
            int col = n0 + wn + ni * 16 + l15;
            float bia = bias[col];
#pragma unroll
            for (int r = 0; r < 4; ++r) {
                float v = acc[mi][ni][r] + bia;
                int rr = rowb + r;
                if (mode == 0) {
                    int b = rr >> 11;
                    int s = rr & 2047;
                    int part = col >> 10;
                    int rem  = col & 1023;
                    int h = rem >> 6;
                    int d = rem & 63;
                    size_t bh = (size_t)(b * 16 + h);
                    if (part == 0)
                        Cq[(bh * SEQ + s) * 64 + d] = (__bf16)v;
                    else if (part == 1)
                        Ck[(bh * SEQ + s) * 64 + d] = (__bf16)v;
                    else
                        Cv[(bh * 64 + d) * SEQ + s] = (__bf16)v;   // V transposed
                } else {
                    Cplain[(size_t)rr * N + col] = v;
                }
            }
        }
    }
}

// ---------------------------------------------------------------------------
// MFMA flash attention, S^T formulation:
//   S^T tile = mfma(K-frag, Q-frag)  ->  lane owns one q (=l15) x 16 keys
//   softmax: in-lane reduce + 2 shfl_xor; scalar m/l per lane
//   mask staged in LDS fp32 (coalesced), read as 4x ds_read_b128
// grid (B*H=32, S/64=32); 4 waves x 16 q rows; two barriers/iter (R6 proven).
// ---------------------------------------------------------------------------
__global__ __launch_bounds__(256)
void attn_kernel(const __bf16* __restrict__ Q, const __bf16* __restrict__ Kb,
                 const __bf16* __restrict__ Vtg, const float* __restrict__ mask,
                 __bf16* __restrict__ Out)
{
    __shared__ __attribute__((aligned(16))) __bf16 Vt[64][72];     // [d][key]
    __shared__ __attribute__((aligned(16))) __bf16 Ps[4][16][72];  // wave P [q][key]
    __shared__ __attribute__((aligned(16))) float  Msh[64][68];    // [blk-q][key]

    const int t    = threadIdx.x;
    const int wave = t >> 6;
    const int lane = t & 63;
    const int l15  = lane & 15;
    const int quad = lane >> 4;
    const int bh   = blockIdx.x;
    const int b    = bh >> 4;
    const int h    = bh & 15;
    const int bq0  = blockIdx.y * 64;          // block q base
    const int q0   = bq0 + wave * 16;          // wave q base

    const __bf16* Qp  = Q   + (size_t)bh * SEQ * 64;
    const __bf16* Kp  = Kb  + (size_t)bh * SEQ * 64;
    const __bf16* Vtp = Vtg + (size_t)bh * 64 * SEQ;   // [d][s]
    const float*  Mp  = mask + (size_t)b * SEQ * SEQ;

    // Q fragment (lane: q=l15, k=quad*8..): also serves as MFMA B-operand
    bf16x8 qf[2];
#pragma unroll
    for (int ks = 0; ks < 2; ++ks)
        qf[ks] = *(const bf16x8*)(Qp + (size_t)(q0 + l15) * 64 + ks * 32 + quad * 8);

    f32x4 oacc[4] = {};
    float mrun = -1e30f, lrun = 0.f;   // stats for q = l15 (replicated per quad)

    for (int kt = 0; kt < SEQ / 64; ++kt) {
        const int key0 = kt * 64;
        __syncthreads();                       // WAR: prev consumers done
        // ---- stage V^T tile (coalesced) ----
        {
            int idx = t * 8;
#pragma unroll
            for (int it2 = 0; it2 < 2; ++it2) {
                int d  = idx >> 6;
                int ky = idx & 63;
                *(uint4*)(&Vt[d][ky]) =
                    *(const uint4*)(Vtp + (size_t)d * SEQ + key0 + ky);
                idx += 2048;
            }
        }
        // ---- stage mask tile fp32 (coalesced float4) ----
        {
            int id = t * 4;
#pragma unroll
            for (int it2 = 0; it2 < 4; ++it2) {
                int qq = id >> 6;
                int kk = id & 63;
                *(float4*)(&Msh[qq][kk]) =
                    *(const float4*)(Mp + (size_t)(bq0 + qq) * SEQ + key0 + kk);
                id += 1024;
            }
        }
        // ---- S^T = K Q^T : lane gets (key=16nb+4quad+r, q=l15) ----
        f32x4 sa[4];
#pragma unroll
        for (int nb = 0; nb < 4; ++nb) {
            const __bf16* kp = Kp + (size_t)(key0 + nb * 16 + l15) * 64;
            bf16x8 kf0 = *(const bf16x8*)(kp + quad * 8);
            bf16x8 kf1 = *(const bf16x8*)(kp + 32 + quad * 8);
            f32x4 z = {};
            z = __builtin_amdgcn_mfma_f32_16x16x32_bf16(kf0, qf[0], z, 0, 0, 0);
            z = __builtin_amdgcn_mfma_f32_16x16x32_bf16(kf1, qf[1], z, 0, 0, 0);
            sa[nb] = z;
        }
        __syncthreads();                       // RAW: Vt + Msh visible

        // ---- masked scores: mask[q=l15][key 4-consec] as one b128 per nb ----
        float s[4][4];
#pragma unroll
        for (int nb = 0; nb < 4; ++nb) {
            float4 mq = *(const float4*)(&Msh[wave * 16 + l15][nb * 16 + quad * 4]);
            s[nb][0] = sa[nb][0] * 0.125f * mq.x + (mq.x - 1.0f) * 10000.0f;
            s[nb][1] = sa[nb][1] * 0.125f * mq.y + (mq.y - 1.0f) * 10000.0f;
            s[nb][2] = sa[nb][2] * 0.125f * mq.z + (mq.z - 1.0f) * 10000.0f;
            s[nb][3] = sa[nb][3] * 0.125f * mq.w + (mq.w - 1.0f) * 10000.0f;
        }
        // ---- softmax for q=l15: in-lane 16-max/sum + 2 cross-quad shfls ----
        float vmax = s[0][0];
#pragma unroll
        for (int nb = 0; nb < 4; ++nb)
#pragma unroll
            for (int r = 0; r < 4; ++r) vmax = fmaxf(vmax, s[nb][r]);
        vmax = fmaxf(vmax, __shfl_xor(vmax, 16));
        vmax = fmaxf(vmax, __shfl_xor(vmax, 32));
        float mnew  = fmaxf(mrun, vmax);
        float alpha = __expf(mrun - mnew);
        mrun = mnew;
        float psum = 0.f;
#pragma unroll
        for (int nb = 0; nb < 4; ++nb)
#pragma unroll
            for (int r = 0; r < 4; ++r) {
                float p = __expf(s[nb][r] - mnew);
                s[nb][r] = p;
                psum += p;
            }
        psum += __shfl_xor(psum, 16);
        psum += __shfl_xor(psum, 32);
        lrun = lrun * alpha + psum;

        // ---- P store: Ps[wave][q=l15][key], 4 consec keys -> b64 writes ----
#pragma unroll
        for (int nb = 0; nb < 4; ++nb) {
            __bf16 pk[4] = { (__bf16)s[nb][0], (__bf16)s[nb][1],
                             (__bf16)s[nb][2], (__bf16)s[nb][3] };
            *(uint2*)(&Ps[wave][l15][nb * 16 + quad * 4]) = *(uint2*)pk;
        }
        // ---- O rescale: alpha for q-rows quad*4+r via bpermute ----
        float arow_[4];
#pragma unroll
        for (int r = 0; r < 4; ++r)
            arow_[r] = __shfl(alpha, quad * 4 + r);
#pragma unroll
        for (int cb = 0; cb < 4; ++cb)
#pragma unroll
            for (int r = 0; r < 4; ++r)
                oacc[cb][r] *= arow_[r];
        // ---- O += P V (pf wave-private: lgkm ordering, no barrier) ----
        bf16x8 pf[2];
#pragma unroll
        for (int ks = 0; ks < 2; ++ks)
            pf[ks] = *(const bf16x8*)(&Ps[wave][l15][ks * 32 + quad * 8]);
#pragma unroll
        for (int cb = 0; cb < 4; ++cb) {
#pragma unroll
            for (int ks = 0; ks < 2; ++ks) {
                bf16x8 vf = *(const bf16x8*)(&Vt[cb * 16 + l15][ks * 32 + quad * 8]);
                oacc[cb] = __builtin_amdgcn_mfma_f32_16x16x32_bf16(pf[ks], vf, oacc[cb], 0, 0, 0);
            }
        }
    }
    // epilogue: lrun for q-rows quad*4+r via bpermute
    float lr[4];
#pragma unroll
    for (int r = 0; r < 4; ++r)
        lr[r] = __shfl(lrun, quad * 4 + r);
#pragma unroll
    for (int cb = 0; cb < 4; ++cb) {
#pragma unroll
        for (int r = 0; r < 4; ++r) {
            int qq = q0 + quad * 4 + r;
            float v = oacc[cb][r] / lr[r];
            Out[((size_t)(b * SEQ + qq)) * DMODEL + h * 64 + cb * 16 + l15] = (__bf16)v;
        }
    }
}

// ---------------------------------------------------------------------------
extern "C" void kernel_launch(void* const* d_in, const int* in_sizes, int n_in,
                              void* d_out, int out_size, void* d_ws, size_t ws_size,
                              hipStream_t stream)
{
    const float* src  = nullptr;  // 4194304
    const float* mask = nullptr;  // 8388608
    const float* Wqkv = nullptr;  // 3145728
    const float* bqkv = nullptr;  // 3072
    const float* Wout = nullptr;  // 1048576
    const float* bout = nullptr;  // 1024
    for (int i = 0; i < n_in; ++i) {
        switch (in_sizes[i]) {
            case 4194304: src  = (const float*)d_in[i]; break;
            case 8388608: mask = (const float*)d_in[i]; break;
            case 3145728: Wqkv = (const float*)d_in[i]; break;
            case 3072:    bqkv = (const float*)d_in[i]; break;
            case 1048576: Wout = (const float*)d_in[i]; break;
            case 1024:    bout = (const float*)d_in[i]; break;
        }
    }
    float* out = (float*)d_out;                  // [2,2048,1024] fp32

    const size_t NE = (size_t)2 * 16 * SEQ * 64; // 4M elems
    __bf16* Qb     = (__bf16*)d_ws;              // 4M
    __bf16* Kb     = Qb + NE;                    // 4M
    __bf16* Ao     = Kb + NE;                    // 4M (attn output)
    __bf16* Vtg    = Ao + NE;                    // 4M  V transposed [bh][d][s]
    __bf16* Wqkv_t = Vtg + NE;                   // 3M  [3072][1024]
    __bf16* Wout_t = Wqkv_t + (size_t)3072 * 1024; // 1M [1024][1024]

    transpose_f32_to_bf16<<<dim3(3072 / 32, 1024 / 32), 256, 0, stream>>>(
        Wqkv, Wqkv_t, 1024, 3072);
    transpose_f32_to_bf16<<<dim3(1024 / 32, 1024 / 32), 256, 0, stream>>>(
        Wout, Wout_t, 1024, 1024);

    // GEMM1: src(f32) @ Wqkv -> Q,K normal; V directly transposed
    gemm_kernel<true><<<dim3(3072 / 128, 4096 / 128), 256, 0, stream>>>(
        (const void*)src, Wqkv_t, bqkv, Qb, Kb, Vtg, nullptr, 1024, 3072, 0);

    attn_kernel<<<dim3(32, SEQ / 64), 256, 0, stream>>>(Qb, Kb, Vtg, mask, Ao);

    gemm_kernel<false><<<dim3(1024 / 128, 4096 / 128), 256, 0, stream>>>(
        (const void*)Ao, Wout_t, bout, nullptr, nullptr, nullptr, out, 1024, 1024, 1);
}